// Round 1
// baseline (5883.748 us; speedup 1.0000x reference)
//
#include <hip/hip_runtime.h>

// ---------------------------------------------------------------------------
// SignLLM forward: encoder -> LN/ReLU -> enc2 -> VQ -> (codebook tables for
// projector & GRU-input) -> MMD via histogram -> persistent-kernel GRU ->
// head GEMM with fused sq-err reduction -> 4 scalar losses.
// ---------------------------------------------------------------------------

typedef __attribute__((ext_vector_type(4))) float  f32x4;
typedef __attribute__((ext_vector_type(8))) short  s16x8;
typedef __attribute__((ext_vector_type(4))) short  s16x4;
typedef __attribute__((ext_vector_type(8))) __bf16 bf16x8;

__device__ __forceinline__ short f2bf(float f) {
  __bf16 h = (__bf16)f;
  return __builtin_bit_cast(short, h);
}
__device__ __forceinline__ float bf2f(short s) {
  return (float)__builtin_bit_cast(__bf16, s);
}
__device__ __forceinline__ f32x4 mfma16(s16x8 a, s16x8 b, f32x4 c) {
  return __builtin_amdgcn_mfma_f32_16x16x32_bf16(
      __builtin_bit_cast(bf16x8, a), __builtin_bit_cast(bf16x8, b), c, 0, 0, 0);
}

// ---------------------------------------------------------------------------
// Generic bf16 MFMA GEMM: C[M,N] = A[M,K] @ B[K,N] + bias, tile 128x128, BK=64
// EPI: 0 = store f32, 1 = store bf16, 2 = relu+store bf16,
//      3 = no store; accumulate sum((C - Xref)^2) into accum (head loss)
// ---------------------------------------------------------------------------
template<bool AF32, int EPI>
__global__ __launch_bounds__(256)
void gemm_k(const void* __restrict__ Ap, const float* __restrict__ Bp,
            const float* __restrict__ bias, void* __restrict__ Cp,
            const float* __restrict__ Xref, float* __restrict__ accum,
            int M, int N, int K)
{
  __shared__ short As[128][72];   // row-major [m][k], padded
  __shared__ short Bs[128][72];   // col-major [n][k], padded
  const int tid  = threadIdx.x;
  const long bm  = (long)blockIdx.x * 128;
  const long bn  = (long)blockIdx.y * 128;
  const int wave = tid >> 6, lane = tid & 63;
  const int wm = (wave >> 1) * 64, wn = (wave & 1) * 64;
  const int l16 = lane & 15, quad = lane >> 4;

  f32x4 acc[4][4];
#pragma unroll
  for (int i = 0; i < 4; ++i)
#pragma unroll
    for (int j = 0; j < 4; ++j) acc[i][j] = (f32x4){0.f, 0.f, 0.f, 0.f};

  const int atc = tid & 15, atr = tid >> 4;   // A staging: 16 cols x 16 rows
  const int btc = tid & 31, btr = tid >> 5;   // B staging: 32 cols x 8 rows

  for (int kt = 0; kt < K; kt += 64) {
    // stage A (convert fp32 -> bf16 if needed)
#pragma unroll
    for (int p = 0; p < 8; ++p) {
      int r = p * 16 + atr;
      if (AF32) {
        const float* src = (const float*)Ap + (bm + r) * (long)K + kt + atc * 4;
        f32x4 v = *(const f32x4*)src;
        s16x4 s;
        s.x = f2bf(v.x); s.y = f2bf(v.y); s.z = f2bf(v.z); s.w = f2bf(v.w);
        *(s16x4*)&As[r][atc * 4] = s;
      } else {
        const short* src = (const short*)Ap + (bm + r) * (long)K + kt + atc * 4;
        *(s16x4*)&As[r][atc * 4] = *(const s16x4*)src;
      }
    }
    // stage B transposed (always fp32 source)
#pragma unroll
    for (int p = 0; p < 8; ++p) {
      int kk = p * 8 + btr;
      const float* brow = Bp + (long)(kt + kk) * N + bn + btc;
#pragma unroll
      for (int j = 0; j < 4; ++j) Bs[btc + 32 * j][kk] = f2bf(brow[32 * j]);
    }
    __syncthreads();
#pragma unroll
    for (int kk = 0; kk < 64; kk += 32) {
      s16x8 af[4], bf[4];
#pragma unroll
      for (int i = 0; i < 4; ++i)
        af[i] = *(const s16x8*)&As[wm + i * 16 + l16][kk + quad * 8];
#pragma unroll
      for (int j = 0; j < 4; ++j)
        bf[j] = *(const s16x8*)&Bs[wn + j * 16 + l16][kk + quad * 8];
#pragma unroll
      for (int i = 0; i < 4; ++i)
#pragma unroll
        for (int j = 0; j < 4; ++j) acc[i][j] = mfma16(af[i], bf[j], acc[i][j]);
    }
    __syncthreads();
  }

  if (EPI == 3) {
    float ls = 0.f;
#pragma unroll
    for (int i = 0; i < 4; ++i)
#pragma unroll
      for (int j = 0; j < 4; ++j) {
        long col = bn + wn + j * 16 + l16;
        float bv = bias[col];
#pragma unroll
        for (int r = 0; r < 4; ++r) {
          long row = bm + wm + i * 16 + quad * 4 + r;
          float v = acc[i][j][r] + bv;
          float d = v - Xref[row * N + col];
          ls += d * d;
        }
      }
#pragma unroll
    for (int off = 32; off > 0; off >>= 1) ls += __shfl_xor(ls, off, 64);
    if (lane == 0) atomicAdd(accum, ls);
  } else {
#pragma unroll
    for (int i = 0; i < 4; ++i)
#pragma unroll
      for (int j = 0; j < 4; ++j) {
        long col = bn + wn + j * 16 + l16;
        float bv = bias[col];
#pragma unroll
        for (int r = 0; r < 4; ++r) {
          long row = bm + wm + i * 16 + quad * 4 + r;
          float v = acc[i][j][r] + bv;
          if (EPI == 2) v = fmaxf(v, 0.f);
          if (EPI == 0) ((float*)Cp)[row * N + col] = v;
          else          ((short*)Cp)[row * N + col] = f2bf(v);
        }
      }
  }
}

// ---------------------------------------------------------------------------
// LayerNorm(512) + ReLU, fp32 in -> bf16 out. One wave per row.
// ---------------------------------------------------------------------------
__global__ __launch_bounds__(256)
void ln_relu_k(const float* __restrict__ hp, const float* __restrict__ g,
               const float* __restrict__ b, short* __restrict__ out)
{
  const int wave = threadIdx.x >> 6, lane = threadIdx.x & 63;
  const long row = (long)blockIdx.x * 4 + wave;
  const float* hr = hp + row * 512;
  const int c0 = lane * 4, c1 = 256 + lane * 4;
  f32x4 v0 = *(const f32x4*)(hr + c0);
  f32x4 v1 = *(const f32x4*)(hr + c1);
  float s  = v0.x + v0.y + v0.z + v0.w + v1.x + v1.y + v1.z + v1.w;
  float ss = v0.x*v0.x + v0.y*v0.y + v0.z*v0.z + v0.w*v0.w
           + v1.x*v1.x + v1.y*v1.y + v1.z*v1.z + v1.w*v1.w;
#pragma unroll
  for (int off = 32; off > 0; off >>= 1) {
    s  += __shfl_xor(s, off, 64);
    ss += __shfl_xor(ss, off, 64);
  }
  float mu  = s * (1.f / 512.f);
  float var = ss * (1.f / 512.f) - mu * mu;
  float rs  = rsqrtf(var + 1e-5f);
  f32x4 g0 = *(const f32x4*)(g + c0), bb0 = *(const f32x4*)(b + c0);
  f32x4 g1 = *(const f32x4*)(g + c1), bb1 = *(const f32x4*)(b + c1);
  s16x4 o0, o1;
#pragma unroll
  for (int e = 0; e < 4; ++e) {
    o0[e] = f2bf(fmaxf((v0[e] - mu) * rs * g0[e] + bb0[e], 0.f));
    o1[e] = f2bf(fmaxf((v1[e] - mu) * rs * g1[e] + bb1[e], 0.f));
  }
  *(s16x4*)(out + row * 512 + c0) = o0;
  *(s16x4*)(out + row * 512 + c1) = o1;
}

// ---------------------------------------------------------------------------
// Codebook prep: cbT[k][n] = codebook[n][k] (fp32), cbBias[n] = -0.5*||c_n||^2
// ---------------------------------------------------------------------------
__global__ __launch_bounds__(256)
void prep_cb_k(const float* __restrict__ cb, float* __restrict__ cbT,
               float* __restrict__ cbBias)
{
  __shared__ float red[256];
  const int r = blockIdx.x, tid = threadIdx.x;
  const float* row = cb + (long)r * 1024;
  float ss = 0.f;
  for (int c = tid; c < 1024; c += 256) {
    float v = row[c];
    cbT[(long)c * 256 + r] = v;
    ss += v * v;
  }
  red[tid] = ss; __syncthreads();
  for (int st = 128; st > 0; st >>= 1) {
    if (tid < st) red[tid] += red[tid + st];
    __syncthreads();
  }
  if (tid == 0) cbBias[r] = -0.5f * red[0];
}

// ---------------------------------------------------------------------------
// VQ: per-row argmax of scores (=f.c - .5||c||^2) + e_latent accumulation
// ---------------------------------------------------------------------------
__global__ __launch_bounds__(256)
void vq_k(const float* __restrict__ sc, const short* __restrict__ feat,
          int* __restrict__ idxp, float* __restrict__ e_acc)
{
  __shared__ float ep[4];
  const int wave = threadIdx.x >> 6, lane = threadIdx.x & 63;
  const long row = (long)blockIdx.x * 4 + wave;
  f32x4 s = *(const f32x4*)(sc + row * 256 + lane * 4);
  float best = s.x; int bi = lane * 4;
  if (s.y > best) { best = s.y; bi = lane * 4 + 1; }
  if (s.z > best) { best = s.z; bi = lane * 4 + 2; }
  if (s.w > best) { best = s.w; bi = lane * 4 + 3; }
#pragma unroll
  for (int off = 32; off > 0; off >>= 1) {
    float ov = __shfl_xor(best, off, 64);
    int   oi = __shfl_xor(bi, off, 64);
    if (ov > best || (ov == best && oi < bi)) { best = ov; bi = oi; }
  }
  const short* fr = feat + row * 1024;
  float sq = 0.f;
#pragma unroll
  for (int p = 0; p < 2; ++p) {
    s16x8 v = *(const s16x8*)(fr + p * 512 + lane * 8);
#pragma unroll
    for (int e = 0; e < 8; ++e) { float f = bf2f(v[e]); sq += f * f; }
  }
#pragma unroll
  for (int off = 32; off > 0; off >>= 1) sq += __shfl_xor(sq, off, 64);
  if (lane == 0) { idxp[row] = bi; ep[wave] = sq - 2.f * best; }
  __syncthreads();
  if (threadIdx.x == 0) atomicAdd(e_acc, ep[0] + ep[1] + ep[2] + ep[3]);
}

// ---------------------------------------------------------------------------
// Per-batch code histogram -> xm[b,:] = (hist/512) @ aligned_codes
// ---------------------------------------------------------------------------
__global__ __launch_bounds__(256)
void hist_xm_k(const int* __restrict__ idxp, const float* __restrict__ AC,
               float* __restrict__ xm)
{
  __shared__ int   hist[256];
  __shared__ float hf[256];
  const int b = blockIdx.x, tid = threadIdx.x;
  hist[tid] = 0; __syncthreads();
  for (int t = tid; t < 512; t += 256) atomicAdd(&hist[idxp[b * 512 + t]], 1);
  __syncthreads();
  hf[tid] = (float)hist[tid] * (1.f / 512.f);
  __syncthreads();
  for (int d = tid; d < 1024; d += 256) {
    float a = 0.f;
    for (int k = 0; k < 256; ++k) a += hf[k] * AC[(long)k * 1024 + d];
    xm[(long)b * 1024 + d] = a;
  }
}

// ---------------------------------------------------------------------------
// MMD: one block, 1024 threads = 32x32 pairs; xm staged in LDS (padded)
// ---------------------------------------------------------------------------
__global__ __launch_bounds__(1024)
void mmd_k(const float* __restrict__ xm, const float* __restrict__ prior,
           float* __restrict__ mmd_out)
{
  extern __shared__ float xs[];   // [32][1028]
  __shared__ float red[48];
  const int tid = threadIdx.x;
  for (int i = tid; i < 32 * 1024; i += 1024)
    xs[(i >> 10) * 1028 + (i & 1023)] = xm[i];
  __syncthreads();
  const int i = tid >> 5, j = tid & 31;
  const float* xi = xs + i * 1028;
  const float* xj = xs + j * 1028;
  const float* pi = prior + (long)i * 1024;
  const float* pj = prior + (long)j * 1024;
  float dxx = 0.f, dyy = 0.f, dxy = 0.f;
  for (int d = 0; d < 1024; d += 4) {
    f32x4 a = *(const f32x4*)(xi + d);
    f32x4 b = *(const f32x4*)(xj + d);
    f32x4 p = *(const f32x4*)(pi + d);
    f32x4 q = *(const f32x4*)(pj + d);
#pragma unroll
    for (int e = 0; e < 4; ++e) {
      float t1 = a[e] - b[e]; dxx += t1 * t1;
      float t2 = p[e] - q[e]; dyy += t2 * t2;
      float t3 = a[e] - q[e]; dxy += t3 * t3;
    }
  }
  float kxx = __expf(-dxx * (1.f / 1024.f));
  float kyy = __expf(-dyy * (1.f / 1024.f));
  float kxy = __expf(-dxy * (1.f / 1024.f));
  const int wv = tid >> 6, lane = tid & 63;
#pragma unroll
  for (int off = 32; off > 0; off >>= 1) {
    kxx += __shfl_xor(kxx, off, 64);
    kyy += __shfl_xor(kyy, off, 64);
    kxy += __shfl_xor(kxy, off, 64);
  }
  if (lane == 0) { red[wv] = kxx; red[16 + wv] = kyy; red[32 + wv] = kxy; }
  __syncthreads();
  if (tid == 0) {
    float sxx = 0.f, syy = 0.f, sxy = 0.f;
    for (int w = 0; w < 16; ++w) {
      sxx += red[w]; syy += red[16 + w]; sxy += red[32 + w];
    }
    mmd_out[0] = (sxx + syy - 2.f * sxy) * (1.f / 1024.f);
  }
}

// ---------------------------------------------------------------------------
// Persistent GRU: 64 WGs x 128 thr (1 WG/CU, co-resident). WG g owns hidden
// dims [g*16, g*16+16): Whh slice (48 cols) bf16 in LDS. Per step: MFMA
// gh = h @ Whh_slice, gather gx from per-code table, gate math, store h/ctx,
// custom agent-scope grid barrier (monotonic counter + flag).
// ---------------------------------------------------------------------------
__global__ __launch_bounds__(128)
void gru_k(const float* __restrict__ Whh, const float* __restrict__ bhh,
           const float* __restrict__ cgx, const int* __restrict__ idxp,
           short* __restrict__ hbuf, short* __restrict__ ctx,
           int* __restrict__ bar)
{
  extern __shared__ short Bsl[];   // [48][1032] bf16
  const int tid = threadIdx.x, g = blockIdx.x;
  const int wave = tid >> 6, lane = tid & 63;
  const int l16 = lane & 15, quad = lane >> 4;

  // stage Whh slice: local col c = gate*16+dl -> global col gate*1024+g*16+dl
  for (int i = tid; i < 48 * 1024; i += 128) {
    int c = i % 48, k = i / 48;
    int gate = c >> 4, dl = c & 15;
    Bsl[c * 1032 + k] = f2bf(Whh[(long)k * 3072 + gate * 1024 + g * 16 + dl]);
  }
  const int dcol = g * 16 + l16;
  const float bhr = bhh[dcol], bhz = bhh[dcol + 1024], bhn = bhh[dcol + 2048];
  const short* arow = hbuf + (long)(wave * 16 + l16) * 1024 + quad * 8;
  const short* b0 = &Bsl[(long)l16 * 1032 + quad * 8];
  const short* b1 = b0 + 16 * 1032;
  const short* b2 = b0 + 32 * 1032;
  float hreg[4] = {0.f, 0.f, 0.f, 0.f};
  int brow[4];
#pragma unroll
  for (int r = 0; r < 4; ++r) brow[r] = wave * 16 + quad * 4 + r;
  __syncthreads();

  for (int t = 0; t < 512; ++t) {
    float xr[4], xz[4], xn[4];
#pragma unroll
    for (int r = 0; r < 4; ++r) {
      int code = idxp[brow[r] * 512 + t];
      const float* gp = cgx + (long)code * 3072 + dcol;
      xr[r] = gp[0]; xz[r] = gp[1024]; xn[r] = gp[2048];
    }
    f32x4 ar_ = {0.f,0.f,0.f,0.f}, az = ar_, an = ar_;
#pragma unroll 4
    for (int ks = 0; ks < 32; ++ks) {
      s16x8 a  = *(const s16x8*)(arow + ks * 32);
      s16x8 vr = *(const s16x8*)(b0 + ks * 32);
      s16x8 vz = *(const s16x8*)(b1 + ks * 32);
      s16x8 vn = *(const s16x8*)(b2 + ks * 32);
      ar_ = mfma16(a, vr, ar_);
      az  = mfma16(a, vz, az);
      an  = mfma16(a, vn, an);
    }
#pragma unroll
    for (int r = 0; r < 4; ++r) {
      float rr = 1.f / (1.f + __expf(-(xr[r] + ar_[r] + bhr)));
      float zz = 1.f / (1.f + __expf(-(xz[r] + az[r] + bhz)));
      float nn = tanhf(xn[r] + rr * (an[r] + bhn));
      float h  = (1.f - zz) * nn + zz * hreg[r];
      hreg[r] = h;
      short hb = f2bf(h);
      hbuf[(long)brow[r] * 1024 + dcol] = hb;
      ctx[((long)brow[r] * 512 + t) * 1024 + dcol] = hb;
    }
    __syncthreads();   // drain all WG stores (vmcnt(0) before s_barrier)
    if (tid == 0) {
      int old = __hip_atomic_fetch_add(&bar[0], 1, __ATOMIC_ACQ_REL,
                                       __HIP_MEMORY_SCOPE_AGENT);
      if (old == 64 * (t + 1) - 1) {
        __hip_atomic_store(&bar[1], t + 1, __ATOMIC_RELEASE,
                           __HIP_MEMORY_SCOPE_AGENT);
      } else {
        while (__hip_atomic_load(&bar[1], __ATOMIC_RELAXED,
                                 __HIP_MEMORY_SCOPE_AGENT) < t + 1) {}
        (void)__hip_atomic_load(&bar[1], __ATOMIC_ACQUIRE,
                                __HIP_MEMORY_SCOPE_AGENT);
      }
    }
    __syncthreads();
  }
}

// ---------------------------------------------------------------------------
__global__ void fin_k(const float* __restrict__ scal, float* __restrict__ out)
{
  float recon = scal[3] * (1.f / 16777216.f);
  float vq    = 1.25f * scal[2] * (1.f / 16777216.f);
  float mmd   = scal[4];
  out[0] = recon;
  out[1] = vq;
  out[2] = mmd;
  out[3] = recon + vq + 0.5f * mmd;
}

// ---------------------------------------------------------------------------
extern "C" void kernel_launch(void* const* d_in, const int* in_sizes, int n_in,
                              void* d_out, int out_size, void* d_ws, size_t ws_size,
                              hipStream_t stream)
{
  const float* x     = (const float*)d_in[0];
  const float* prior = (const float*)d_in[1];
  const float* encW1 = (const float*)d_in[2];
  const float* encb1 = (const float*)d_in[3];
  const float* lng   = (const float*)d_in[4];
  const float* lnb   = (const float*)d_in[5];
  const float* encW2 = (const float*)d_in[6];
  const float* encb2 = (const float*)d_in[7];
  const float* cb    = (const float*)d_in[8];
  const float* pW1   = (const float*)d_in[9];
  const float* pb1   = (const float*)d_in[10];
  const float* pW2   = (const float*)d_in[11];
  const float* pb2   = (const float*)d_in[12];
  const float* Wih   = (const float*)d_in[13];
  const float* Whh   = (const float*)d_in[14];
  const float* bih   = (const float*)d_in[15];
  const float* bhh   = (const float*)d_in[16];
  const float* headW = (const float*)d_in[17];
  const float* headb = (const float*)d_in[18];

  // workspace layout (total 89,654,528 B)
  char* ws = (char*)d_ws;
  if (ws_size < 89654528) return;
  float* h_pre  = (float*)(ws + 0);           // 32 MB (scores alias after LN)
  float* scores = h_pre;
  short* h1     = (short*)(ws + 33554432);    // 16 MB
  short* feat   = (short*)(ws + 50331648);    // 32 MB (ctx alias after VQ)
  short* ctx    = feat;
  float* cgx    = (float*)(ws + 83886080);    // 3 MB  code_gx = cb@Wih+bih
  float* AC     = (float*)(ws + 87031808);    // 1 MB  aligned codes
  float* cbT    = (float*)(ws + 88080384);    // 1 MB  codebook^T f32
  short* ch     = (short*)(ws + 89128960);    // 256 KB codes hidden (bf16)
  float* xm     = (float*)(ws + 89391104);    // 128 KB
  int*   idxp   = (int*)  (ws + 89522176);    // 64 KB
  short* hbuf   = (short*)(ws + 89587712);    // 64 KB GRU h state (bf16)
  float* scal   = (float*)(ws + 89653248);    // 256 B scalars
  int*   bar    = (int*)scal;                 // [0]=cnt [1]=flag
  float* e_acc  = scal + 2;
  float* r_acc  = scal + 3;
  float* mmdv   = scal + 4;
  float* cbBias = (float*)(ws + 89653504);    // 1 KB

  // zero h state + barrier/accumulators (ws is poisoned 0xAA each launch)
  hipMemsetAsync(ws + 89587712, 0, 65536 + 256, stream);

  dim3 blk(256);
  // codebook transpose + score bias
  prep_cb_k<<<256, blk, 0, stream>>>(cb, cbT, cbBias);
  // encoder layer 1: x @ W1 + b1 -> h_pre (f32)
  gemm_k<true, 0><<<dim3(128, 4), blk, 0, stream>>>(
      x, encW1, encb1, h_pre, nullptr, nullptr, 16384, 512, 1024);
  // LN + ReLU -> h1 (bf16)
  ln_relu_k<<<4096, blk, 0, stream>>>(h_pre, lng, lnb, h1);
  // encoder layer 2: h1 @ W2 + b2 -> feat (bf16)
  gemm_k<false, 1><<<dim3(128, 8), blk, 0, stream>>>(
      h1, encW2, encb2, feat, nullptr, nullptr, 16384, 1024, 512);
  // VQ scores: feat @ cbT - 0.5||c||^2 -> scores (f32, aliases h_pre)
  gemm_k<false, 0><<<dim3(128, 2), blk, 0, stream>>>(
      feat, cbT, cbBias, scores, nullptr, nullptr, 16384, 256, 1024);
  // argmax + e_latent
  vq_k<<<4096, blk, 0, stream>>>(scores, feat, idxp, e_acc);
  // per-code tables: projector hidden (relu, bf16), aligned codes, gru gx
  gemm_k<true, 2><<<dim3(2, 4), blk, 0, stream>>>(
      cb, pW1, pb1, ch, nullptr, nullptr, 256, 512, 1024);
  gemm_k<false, 0><<<dim3(2, 8), blk, 0, stream>>>(
      ch, pW2, pb2, AC, nullptr, nullptr, 256, 1024, 512);
  gemm_k<true, 0><<<dim3(2, 24), blk, 0, stream>>>(
      cb, Wih, bih, cgx, nullptr, nullptr, 256, 3072, 1024);
  // MMD path
  hist_xm_k<<<32, blk, 0, stream>>>(idxp, AC, xm);
  mmd_k<<<1, 1024, 32 * 1028 * 4, stream>>>(xm, prior, mmdv);
  // persistent GRU (writes ctx, aliases feat region)
  gru_k<<<64, 128, 48 * 1032 * 2, stream>>>(Whh, bhh, cgx, idxp, hbuf, ctx, bar);
  // head GEMM + fused recon sq-err reduction
  gemm_k<false, 3><<<dim3(128, 8), blk, 0, stream>>>(
      ctx, headW, headb, nullptr, x, r_acc, 16384, 1024, 1024);
  // final scalars
  fin_k<<<1, 1, 0, stream>>>(scal, (float*)d_out);
}

// Round 2
// 5739.905 us; speedup vs baseline: 1.0251x; 1.0251x over previous
//
#include <hip/hip_runtime.h>

// ---------------------------------------------------------------------------
// SignLLM forward: encoder -> LN/ReLU -> enc2 -> VQ -> (codebook tables for
// projector & GRU-input) -> MMD via histogram -> persistent-kernel GRU ->
// head GEMM with fused sq-err reduction -> 4 scalar losses.
// Round 2: GRU grid sync rebuilt around uncached (sc1) h exchange +
// distributed per-wave epoch flags; zero cache-maintenance in the loop;
// double-buffered h state.
// ---------------------------------------------------------------------------

typedef __attribute__((ext_vector_type(4))) float  f32x4;
typedef __attribute__((ext_vector_type(8))) short  s16x8;
typedef __attribute__((ext_vector_type(4))) short  s16x4;
typedef __attribute__((ext_vector_type(8))) __bf16 bf16x8;
typedef unsigned long long u64;
typedef unsigned int       u32;

__device__ __forceinline__ short f2bf(float f) {
  __bf16 h = (__bf16)f;
  return __builtin_bit_cast(short, h);
}
__device__ __forceinline__ float bf2f(short s) {
  return (float)__builtin_bit_cast(__bf16, s);
}
__device__ __forceinline__ f32x4 mfma16(s16x8 a, s16x8 b, f32x4 c) {
  return __builtin_amdgcn_mfma_f32_16x16x32_bf16(
      __builtin_bit_cast(bf16x8, a), __builtin_bit_cast(bf16x8, b), c, 0, 0, 0);
}
__device__ __forceinline__ void vm_drain() {
  asm volatile("s_waitcnt vmcnt(0)" ::: "memory");
}
__device__ __forceinline__ u64 ld_uc64(const u64* p) {
  return __hip_atomic_load(p, __ATOMIC_RELAXED, __HIP_MEMORY_SCOPE_AGENT);
}
__device__ __forceinline__ void st_uc32(u32* p, u32 v) {
  __hip_atomic_store(p, v, __ATOMIC_RELAXED, __HIP_MEMORY_SCOPE_AGENT);
}

// ---------------------------------------------------------------------------
// Generic bf16 MFMA GEMM: C[M,N] = A[M,K] @ B[K,N] + bias, tile 128x128, BK=64
// EPI: 0 = store f32, 1 = store bf16, 2 = relu+store bf16,
//      3 = no store; accumulate sum((C - Xref)^2) into accum (head loss)
// ---------------------------------------------------------------------------
template<bool AF32, int EPI>
__global__ __launch_bounds__(256)
void gemm_k(const void* __restrict__ Ap, const float* __restrict__ Bp,
            const float* __restrict__ bias, void* __restrict__ Cp,
            const float* __restrict__ Xref, float* __restrict__ accum,
            int M, int N, int K)
{
  __shared__ short As[128][72];   // row-major [m][k], padded
  __shared__ short Bs[128][72];   // col-major [n][k], padded
  const int tid  = threadIdx.x;
  const long bm  = (long)blockIdx.x * 128;
  const long bn  = (long)blockIdx.y * 128;
  const int wave = tid >> 6, lane = tid & 63;
  const int wm = (wave >> 1) * 64, wn = (wave & 1) * 64;
  const int l16 = lane & 15, quad = lane >> 4;

  f32x4 acc[4][4];
#pragma unroll
  for (int i = 0; i < 4; ++i)
#pragma unroll
    for (int j = 0; j < 4; ++j) acc[i][j] = (f32x4){0.f, 0.f, 0.f, 0.f};

  const int atc = tid & 15, atr = tid >> 4;   // A staging: 16 cols x 16 rows
  const int btc = tid & 31, btr = tid >> 5;   // B staging: 32 cols x 8 rows

  for (int kt = 0; kt < K; kt += 64) {
#pragma unroll
    for (int p = 0; p < 8; ++p) {
      int r = p * 16 + atr;
      if (AF32) {
        const float* src = (const float*)Ap + (bm + r) * (long)K + kt + atc * 4;
        f32x4 v = *(const f32x4*)src;
        s16x4 s;
        s.x = f2bf(v.x); s.y = f2bf(v.y); s.z = f2bf(v.z); s.w = f2bf(v.w);
        *(s16x4*)&As[r][atc * 4] = s;
      } else {
        const short* src = (const short*)Ap + (bm + r) * (long)K + kt + atc * 4;
        *(s16x4*)&As[r][atc * 4] = *(const s16x4*)src;
      }
    }
#pragma unroll
    for (int p = 0; p < 8; ++p) {
      int kk = p * 8 + btr;
      const float* brow = Bp + (long)(kt + kk) * N + bn + btc;
#pragma unroll
      for (int j = 0; j < 4; ++j) Bs[btc + 32 * j][kk] = f2bf(brow[32 * j]);
    }
    __syncthreads();
#pragma unroll
    for (int kk = 0; kk < 64; kk += 32) {
      s16x8 af[4], bf[4];
#pragma unroll
      for (int i = 0; i < 4; ++i)
        af[i] = *(const s16x8*)&As[wm + i * 16 + l16][kk + quad * 8];
#pragma unroll
      for (int j = 0; j < 4; ++j)
        bf[j] = *(const s16x8*)&Bs[wn + j * 16 + l16][kk + quad * 8];
#pragma unroll
      for (int i = 0; i < 4; ++i)
#pragma unroll
        for (int j = 0; j < 4; ++j) acc[i][j] = mfma16(af[i], bf[j], acc[i][j]);
    }
    __syncthreads();
  }

  if (EPI == 3) {
    float ls = 0.f;
#pragma unroll
    for (int i = 0; i < 4; ++i)
#pragma unroll
      for (int j = 0; j < 4; ++j) {
        long col = bn + wn + j * 16 + l16;
        float bv = bias[col];
#pragma unroll
        for (int r = 0; r < 4; ++r) {
          long row = bm + wm + i * 16 + quad * 4 + r;
          float v = acc[i][j][r] + bv;
          float d = v - Xref[row * N + col];
          ls += d * d;
        }
      }
#pragma unroll
    for (int off = 32; off > 0; off >>= 1) ls += __shfl_xor(ls, off, 64);
    if (lane == 0) atomicAdd(accum, ls);
  } else {
#pragma unroll
    for (int i = 0; i < 4; ++i)
#pragma unroll
      for (int j = 0; j < 4; ++j) {
        long col = bn + wn + j * 16 + l16;
        float bv = bias[col];
#pragma unroll
        for (int r = 0; r < 4; ++r) {
          long row = bm + wm + i * 16 + quad * 4 + r;
          float v = acc[i][j][r] + bv;
          if (EPI == 2) v = fmaxf(v, 0.f);
          if (EPI == 0) ((float*)Cp)[row * N + col] = v;
          else          ((short*)Cp)[row * N + col] = f2bf(v);
        }
      }
  }
}

// ---------------------------------------------------------------------------
// LayerNorm(512) + ReLU, fp32 in -> bf16 out. One wave per row.
// ---------------------------------------------------------------------------
__global__ __launch_bounds__(256)
void ln_relu_k(const float* __restrict__ hp, const float* __restrict__ g,
               const float* __restrict__ b, short* __restrict__ out)
{
  const int wave = threadIdx.x >> 6, lane = threadIdx.x & 63;
  const long row = (long)blockIdx.x * 4 + wave;
  const float* hr = hp + row * 512;
  const int c0 = lane * 4, c1 = 256 + lane * 4;
  f32x4 v0 = *(const f32x4*)(hr + c0);
  f32x4 v1 = *(const f32x4*)(hr + c1);
  float s  = v0.x + v0.y + v0.z + v0.w + v1.x + v1.y + v1.z + v1.w;
  float ss = v0.x*v0.x + v0.y*v0.y + v0.z*v0.z + v0.w*v0.w
           + v1.x*v1.x + v1.y*v1.y + v1.z*v1.z + v1.w*v1.w;
#pragma unroll
  for (int off = 32; off > 0; off >>= 1) {
    s  += __shfl_xor(s, off, 64);
    ss += __shfl_xor(ss, off, 64);
  }
  float mu  = s * (1.f / 512.f);
  float var = ss * (1.f / 512.f) - mu * mu;
  float rs  = rsqrtf(var + 1e-5f);
  f32x4 g0 = *(const f32x4*)(g + c0), bb0 = *(const f32x4*)(b + c0);
  f32x4 g1 = *(const f32x4*)(g + c1), bb1 = *(const f32x4*)(b + c1);
  s16x4 o0, o1;
#pragma unroll
  for (int e = 0; e < 4; ++e) {
    o0[e] = f2bf(fmaxf((v0[e] - mu) * rs * g0[e] + bb0[e], 0.f));
    o1[e] = f2bf(fmaxf((v1[e] - mu) * rs * g1[e] + bb1[e], 0.f));
  }
  *(s16x4*)(out + row * 512 + c0) = o0;
  *(s16x4*)(out + row * 512 + c1) = o1;
}

// ---------------------------------------------------------------------------
// Codebook prep: cbT[k][n] = codebook[n][k] (fp32), cbBias[n] = -0.5*||c_n||^2
// ---------------------------------------------------------------------------
__global__ __launch_bounds__(256)
void prep_cb_k(const float* __restrict__ cb, float* __restrict__ cbT,
               float* __restrict__ cbBias)
{
  __shared__ float red[256];
  const int r = blockIdx.x, tid = threadIdx.x;
  const float* row = cb + (long)r * 1024;
  float ss = 0.f;
  for (int c = tid; c < 1024; c += 256) {
    float v = row[c];
    cbT[(long)c * 256 + r] = v;
    ss += v * v;
  }
  red[tid] = ss; __syncthreads();
  for (int st = 128; st > 0; st >>= 1) {
    if (tid < st) red[tid] += red[tid + st];
    __syncthreads();
  }
  if (tid == 0) cbBias[r] = -0.5f * red[0];
}

// ---------------------------------------------------------------------------
// VQ: per-row argmax of scores (=f.c - .5||c||^2) + e_latent accumulation
// ---------------------------------------------------------------------------
__global__ __launch_bounds__(256)
void vq_k(const float* __restrict__ sc, const short* __restrict__ feat,
          int* __restrict__ idxp, float* __restrict__ e_acc)
{
  __shared__ float ep[4];
  const int wave = threadIdx.x >> 6, lane = threadIdx.x & 63;
  const long row = (long)blockIdx.x * 4 + wave;
  f32x4 s = *(const f32x4*)(sc + row * 256 + lane * 4);
  float best = s.x; int bi = lane * 4;
  if (s.y > best) { best = s.y; bi = lane * 4 + 1; }
  if (s.z > best) { best = s.z; bi = lane * 4 + 2; }
  if (s.w > best) { best = s.w; bi = lane * 4 + 3; }
#pragma unroll
  for (int off = 32; off > 0; off >>= 1) {
    float ov = __shfl_xor(best, off, 64);
    int   oi = __shfl_xor(bi, off, 64);
    if (ov > best || (ov == best && oi < bi)) { best = ov; bi = oi; }
  }
  const short* fr = feat + row * 1024;
  float sq = 0.f;
#pragma unroll
  for (int p = 0; p < 2; ++p) {
    s16x8 v = *(const s16x8*)(fr + p * 512 + lane * 8);
#pragma unroll
    for (int e = 0; e < 8; ++e) { float f = bf2f(v[e]); sq += f * f; }
  }
#pragma unroll
  for (int off = 32; off > 0; off >>= 1) sq += __shfl_xor(sq, off, 64);
  if (lane == 0) { idxp[row] = bi; ep[wave] = sq - 2.f * best; }
  __syncthreads();
  if (threadIdx.x == 0) atomicAdd(e_acc, ep[0] + ep[1] + ep[2] + ep[3]);
}

// ---------------------------------------------------------------------------
// Per-batch code histogram -> xm[b,:] = (hist/512) @ aligned_codes
// ---------------------------------------------------------------------------
__global__ __launch_bounds__(256)
void hist_xm_k(const int* __restrict__ idxp, const float* __restrict__ AC,
               float* __restrict__ xm)
{
  __shared__ int   hist[256];
  __shared__ float hf[256];
  const int b = blockIdx.x, tid = threadIdx.x;
  hist[tid] = 0; __syncthreads();
  for (int t = tid; t < 512; t += 256) atomicAdd(&hist[idxp[b * 512 + t]], 1);
  __syncthreads();
  hf[tid] = (float)hist[tid] * (1.f / 512.f);
  __syncthreads();
  for (int d = tid; d < 1024; d += 256) {
    float a = 0.f;
    for (int k = 0; k < 256; ++k) a += hf[k] * AC[(long)k * 1024 + d];
    xm[(long)b * 1024 + d] = a;
  }
}

// ---------------------------------------------------------------------------
// MMD: one block, 1024 threads = 32x32 pairs; xm staged in LDS (padded)
// ---------------------------------------------------------------------------
__global__ __launch_bounds__(1024)
void mmd_k(const float* __restrict__ xm, const float* __restrict__ prior,
           float* __restrict__ mmd_out)
{
  extern __shared__ float xs[];   // [32][1028]
  __shared__ float red[48];
  const int tid = threadIdx.x;
  for (int i = tid; i < 32 * 1024; i += 1024)
    xs[(i >> 10) * 1028 + (i & 1023)] = xm[i];
  __syncthreads();
  const int i = tid >> 5, j = tid & 31;
  const float* xi = xs + i * 1028;
  const float* xj = xs + j * 1028;
  const float* pi = prior + (long)i * 1024;
  const float* pj = prior + (long)j * 1024;
  float dxx = 0.f, dyy = 0.f, dxy = 0.f;
  for (int d = 0; d < 1024; d += 4) {
    f32x4 a = *(const f32x4*)(xi + d);
    f32x4 b = *(const f32x4*)(xj + d);
    f32x4 p = *(const f32x4*)(pi + d);
    f32x4 q = *(const f32x4*)(pj + d);
#pragma unroll
    for (int e = 0; e < 4; ++e) {
      float t1 = a[e] - b[e]; dxx += t1 * t1;
      float t2 = p[e] - q[e]; dyy += t2 * t2;
      float t3 = a[e] - q[e]; dxy += t3 * t3;
    }
  }
  float kxx = __expf(-dxx * (1.f / 1024.f));
  float kyy = __expf(-dyy * (1.f / 1024.f));
  float kxy = __expf(-dxy * (1.f / 1024.f));
  const int wv = tid >> 6, lane = tid & 63;
#pragma unroll
  for (int off = 32; off > 0; off >>= 1) {
    kxx += __shfl_xor(kxx, off, 64);
    kyy += __shfl_xor(kyy, off, 64);
    kxy += __shfl_xor(kxy, off, 64);
  }
  if (lane == 0) { red[wv] = kxx; red[16 + wv] = kyy; red[32 + wv] = kxy; }
  __syncthreads();
  if (tid == 0) {
    float sxx = 0.f, syy = 0.f, sxy = 0.f;
    for (int w = 0; w < 16; ++w) {
      sxx += red[w]; syy += red[16 + w]; sxy += red[32 + w];
    }
    mmd_out[0] = (sxx + syy - 2.f * sxy) * (1.f / 1024.f);
  }
}

// ---------------------------------------------------------------------------
// Persistent GRU, round 2. 64 WGs x 128 thr. WG g owns hidden dims
// [g*16, g*16+16). h state is exchanged through LLC via uncached (sc1)
// relaxed agent-scope atomics -> no wbl2/inv anywhere, L2 stays warm for
// cgx/idxp. Double-buffered h (race-free). Per-WAVE epoch flags (the two
// waves of a WG touch disjoint batch rows -> no __syncthreads in loop).
// ---------------------------------------------------------------------------
__global__ __launch_bounds__(128, 1)
void gru_k(const float* __restrict__ Whh, const float* __restrict__ bhh,
           const float* __restrict__ cgx, const int* __restrict__ idxp,
           u32* __restrict__ hbuf, u32* __restrict__ ctx,
           int* __restrict__ flags)
{
  extern __shared__ short Bsl[];   // [48][1032] bf16
  const int tid = threadIdx.x, g = blockIdx.x;
  const int wave = tid >> 6, lane = tid & 63;
  const int l16 = lane & 15, quad = lane >> 4;

  // stage Whh slice: local col c = gate*16+dl -> global col gate*1024+g*16+dl
  for (int i = tid; i < 48 * 1024; i += 128) {
    int c = i % 48, k = i / 48;
    int gate = c >> 4, dl = c & 15;
    Bsl[c * 1032 + k] = f2bf(Whh[(long)k * 3072 + gate * 1024 + g * 16 + dl]);
  }
  const int dcol = g * 16 + l16;
  const float bhr = bhh[dcol], bhz = bhh[dcol + 1024], bhn = bhh[dcol + 2048];
  const short* b0 = &Bsl[l16 * 1032 + quad * 8];
  const short* b1 = b0 + 16 * 1032;
  const short* b2 = b0 + 32 * 1032;
  const int arowbase = (wave * 16 + l16) * 512 + quad * 4;  // u32 units
  float hreg[4] = {0.f, 0.f, 0.f, 0.f};
  int brow[4];
#pragma unroll
  for (int r = 0; r < 4; ++r) brow[r] = wave * 16 + quad * 4 + r;
  const int myflag = g * 2 + wave;
  __syncthreads();   // Bsl staged by both waves

  // preload gx for t=0 (cached; L2 stays valid the whole loop)
  float xr[4], xz[4], xn[4];
#pragma unroll
  for (int r = 0; r < 4; ++r) {
    int code = idxp[brow[r] * 512];
    const float* gp = cgx + (long)code * 3072 + dcol;
    xr[r] = gp[0]; xz[r] = gp[1024]; xn[r] = gp[2048];
  }

  for (int t = 0; t < 512; ++t) {
    // wait until all 128 waves have published h for epoch t
    if (t > 0) {
      int a, b;
      do {
        a = __hip_atomic_load(&flags[lane],      __ATOMIC_RELAXED,
                              __HIP_MEMORY_SCOPE_AGENT);
        b = __hip_atomic_load(&flags[64 + lane], __ATOMIC_RELAXED,
                              __HIP_MEMORY_SCOPE_AGENT);
      } while (__any(a < t || b < t));
    }
    // gh = h @ Whh_slice ; h read uncached from buf[t&1]
    const u64* ap = (const u64*)(hbuf + ((t & 1) << 14) + arowbase);
    f32x4 ar_ = {0.f,0.f,0.f,0.f}, az = ar_, an = ar_;
#pragma unroll 8
    for (int ks = 0; ks < 32; ++ks) {
      u64 q0 = ld_uc64(ap + ks * 8);
      u64 q1 = ld_uc64(ap + ks * 8 + 1);
      union { u64 q[2]; s16x8 v; } ua; ua.q[0] = q0; ua.q[1] = q1;
      s16x8 vr = *(const s16x8*)(b0 + ks * 32);
      s16x8 vz = *(const s16x8*)(b1 + ks * 32);
      s16x8 vn = *(const s16x8*)(b2 + ks * 32);
      ar_ = mfma16(ua.v, vr, ar_);
      az  = mfma16(ua.v, vz, az);
      an  = mfma16(ua.v, vn, an);
    }
    // gates
#pragma unroll
    for (int r = 0; r < 4; ++r) {
      float rr = 1.f / (1.f + __expf(-(xr[r] + ar_[r] + bhr)));
      float zz = 1.f / (1.f + __expf(-(xz[r] + az[r] + bhz)));
      float u  = xn[r] + rr * (an[r] + bhn);
      float e  = __expf(-2.f * u);
      float nn = (1.f - e) / (1.f + e);
      hreg[r]  = (1.f - zz) * nn + zz * hreg[r];
    }
    // prefetch gx for t+1 (overlaps the store drain)
    int tn = (t + 1 < 512) ? t + 1 : 0;
#pragma unroll
    for (int r = 0; r < 4; ++r) {
      int code = idxp[brow[r] * 512 + tn];
      const float* gp = cgx + (long)code * 3072 + dcol;
      xr[r] = gp[0]; xz[r] = gp[1024]; xn[r] = gp[2048];
    }
    // pack bf16 pairs; even l16 lanes store h (uncached) + ctx (cached)
    u32* hdst = hbuf + (((t + 1) & 1) << 14);
#pragma unroll
    for (int r = 0; r < 4; ++r) {
      unsigned short hb = (unsigned short)f2bf(hreg[r]);
      u32 other = (u32)__shfl_xor((int)hb, 1, 64) & 0xffffu;
      if ((l16 & 1) == 0) {
        u32 w = (u32)hb | (other << 16);
        st_uc32(hdst + brow[r] * 512 + (dcol >> 1), w);
        ctx[((long)brow[r] * 512 + t) * 512 + (dcol >> 1)] = w;
      }
    }
    vm_drain();   // h stores visible at LLC (and gx prefetch landed)
    if (lane == 0)
      __hip_atomic_store(&flags[myflag], t + 1, __ATOMIC_RELAXED,
                         __HIP_MEMORY_SCOPE_AGENT);
  }
}

// ---------------------------------------------------------------------------
__global__ void fin_k(const float* __restrict__ scal, float* __restrict__ out)
{
  float recon = scal[3] * (1.f / 16777216.f);
  float vq    = 1.25f * scal[2] * (1.f / 16777216.f);
  float mmd   = scal[4];
  out[0] = recon;
  out[1] = vq;
  out[2] = mmd;
  out[3] = recon + vq + 0.5f * mmd;
}

// ---------------------------------------------------------------------------
extern "C" void kernel_launch(void* const* d_in, const int* in_sizes, int n_in,
                              void* d_out, int out_size, void* d_ws, size_t ws_size,
                              hipStream_t stream)
{
  const float* x     = (const float*)d_in[0];
  const float* prior = (const float*)d_in[1];
  const float* encW1 = (const float*)d_in[2];
  const float* encb1 = (const float*)d_in[3];
  const float* lng   = (const float*)d_in[4];
  const float* lnb   = (const float*)d_in[5];
  const float* encW2 = (const float*)d_in[6];
  const float* encb2 = (const float*)d_in[7];
  const float* cb    = (const float*)d_in[8];
  const float* pW1   = (const float*)d_in[9];
  const float* pb1   = (const float*)d_in[10];
  const float* pW2   = (const float*)d_in[11];
  const float* pb2   = (const float*)d_in[12];
  const float* Wih   = (const float*)d_in[13];
  const float* Whh   = (const float*)d_in[14];
  const float* bih   = (const float*)d_in[15];
  const float* bhh   = (const float*)d_in[16];
  const float* headW = (const float*)d_in[17];
  const float* headb = (const float*)d_in[18];

  // workspace layout (total 89,654,528 B, same as round 1)
  char* ws = (char*)d_ws;
  if (ws_size < 89654528) return;
  // offset 0 region is time-shared: h_pre (enc1 out) -> scores (VQ) -> then
  // after vq_k it is memset and becomes hbuf (2x64KB) + flags (512B).
  float* h_pre  = (float*)(ws + 0);           // 32 MB
  float* scores = h_pre;
  u32*   hbuf   = (u32*)(ws + 0);             // 128 KB (after vq_k)
  int*   flags  = (int*)(ws + 131072);        // 512 B
  short* h1     = (short*)(ws + 33554432);    // 16 MB
  short* feat   = (short*)(ws + 50331648);    // 32 MB (ctx alias after VQ)
  u32*   ctx    = (u32*)feat;
  float* cgx    = (float*)(ws + 83886080);    // 3 MB  code_gx = cb@Wih+bih
  float* AC     = (float*)(ws + 87031808);    // 1 MB  aligned codes
  float* cbT    = (float*)(ws + 88080384);    // 1 MB  codebook^T f32
  short* ch     = (short*)(ws + 89128960);    // 256 KB codes hidden (bf16)
  float* xm     = (float*)(ws + 89391104);    // 128 KB
  int*   idxp   = (int*)  (ws + 89522176);    // 64 KB
  float* scal   = (float*)(ws + 89653248);    // 256 B scalars
  float* e_acc  = scal + 2;
  float* r_acc  = scal + 3;
  float* mmdv   = scal + 4;
  float* cbBias = (float*)(ws + 89653504);    // 1 KB

  // zero loss accumulators (ws is poisoned 0xAA each launch)
  hipMemsetAsync(scal, 0, 256, stream);

  dim3 blk(256);
  prep_cb_k<<<256, blk, 0, stream>>>(cb, cbT, cbBias);
  // encoder layer 1: x @ W1 + b1 -> h_pre (f32)
  gemm_k<true, 0><<<dim3(128, 4), blk, 0, stream>>>(
      x, encW1, encb1, h_pre, nullptr, nullptr, 16384, 512, 1024);
  ln_relu_k<<<4096, blk, 0, stream>>>(h_pre, lng, lnb, h1);
  // encoder layer 2: h1 @ W2 + b2 -> feat (bf16)
  gemm_k<false, 1><<<dim3(128, 8), blk, 0, stream>>>(
      h1, encW2, encb2, feat, nullptr, nullptr, 16384, 1024, 512);
  // VQ scores: feat @ cbT - 0.5||c||^2 -> scores (f32, aliases h_pre)
  gemm_k<false, 0><<<dim3(128, 2), blk, 0, stream>>>(
      feat, cbT, cbBias, scores, nullptr, nullptr, 16384, 256, 1024);
  vq_k<<<4096, blk, 0, stream>>>(scores, feat, idxp, e_acc);
  // scores region now dead -> becomes GRU h double-buffer + flags (zeroed)
  hipMemsetAsync(ws, 0, 131072 + 512, stream);
  // per-code tables: projector hidden (relu, bf16), aligned codes, gru gx
  gemm_k<true, 2><<<dim3(2, 4), blk, 0, stream>>>(
      cb, pW1, pb1, ch, nullptr, nullptr, 256, 512, 1024);
  gemm_k<false, 0><<<dim3(2, 8), blk, 0, stream>>>(
      ch, pW2, pb2, AC, nullptr, nullptr, 256, 1024, 512);
  gemm_k<true, 0><<<dim3(2, 24), blk, 0, stream>>>(
      cb, Wih, bih, cgx, nullptr, nullptr, 256, 3072, 1024);
  // MMD path
  hist_xm_k<<<32, blk, 0, stream>>>(idxp, AC, xm);
  mmd_k<<<1, 1024, 32 * 1028 * 4, stream>>>(xm, prior, mmdv);
  // persistent GRU (writes ctx, aliases feat region)
  gru_k<<<64, 128, 48 * 1032 * 2, stream>>>(Whh, bhh, cgx, idxp, hbuf, ctx, flags);
  // head GEMM + fused recon sq-err reduction
  gemm_k<false, 3><<<dim3(128, 8), blk, 0, stream>>>(
      ctx, headW, headb, nullptr, x, r_acc, 16384, 1024, 1024);
  fin_k<<<1, 1, 0, stream>>>(scal, (float*)d_out);
}